// Round 3
// baseline (4892.695 us; speedup 1.0000x reference)
//
#include <hip/hip_runtime.h>
#include <hip/hip_bf16.h>
#include <hip/hip_cooperative_groups.h>

namespace cg = cooperative_groups;

// Problem constants: B=32, S=128, T=20 (19 dec steps), H=1024, D=512, K_attn=100, V=32000
// Inputs float32; output d_out float32 (B,19,V).
// bf16 MFMA with fp32 accumulate; recurrent state fp32 in registers.

using bf16 = __hip_bfloat16;
typedef __attribute__((ext_vector_type(8))) __bf16 bf16x8;
typedef __attribute__((ext_vector_type(4))) float f32x4;

__device__ __forceinline__ bf16x8 ld8(const bf16* p) {
    return *reinterpret_cast<const bf16x8*>(p);
}
__device__ __forceinline__ float b2f(bf16 v) { return __bfloat162float(v); }
__device__ __forceinline__ bf16 f2b(float v) { return __float2bfloat16(v); }
__device__ __forceinline__ float sigf(float x) { return 1.0f / (1.0f + expf(-x)); }

#define MFMA(a, b, c) __builtin_amdgcn_mfma_f32_16x16x32_bf16((a), (b), (c), 0, 0, 0)

// ---------------------------------------------------------------------------
// f32 -> bf16 conversion for weight tensors. blockIdx.y selects tensor.
struct ConvDesc { const float* src; bf16* dst; int n; };
struct ConvTable { ConvDesc d[12]; };

__global__ __launch_bounds__(256) void k_conv(ConvTable tab) {
    ConvDesc cd = tab.d[blockIdx.y];
    int stride = gridDim.x * blockDim.x * 4;
    for (int i = (blockIdx.x * blockDim.x + threadIdx.x) * 4; i < cd.n; i += stride) {
        float4 v = *reinterpret_cast<const float4*>(cd.src + i);
        bf16 tmp[4] = {f2b(v.x), f2b(v.y), f2b(v.z), f2b(v.w)};
        *reinterpret_cast<ushort4*>(cd.dst + i) = *reinterpret_cast<const ushort4*>(tmp);
    }
}

// ---------------------------------------------------------------------------
// Gather bf16 embedding rows (512 bf16 = 256 u32 per row), one block per row.
__global__ __launch_bounds__(256) void k_gather(const unsigned int* __restrict__ table,
                                                const int* __restrict__ idx,
                                                unsigned int* __restrict__ out) {
    int r = blockIdx.x;
    out[(size_t)r * 256 + threadIdx.x] = table[(size_t)idx[r] * 256 + threadIdx.x];
}

// ---------------------------------------------------------------------------
// Generic big tiled GEMM: C = A(MxK) @ Bw(NxK)^T  (both row-major, bf16)
// 128x128 tile per block, 4 waves each 64x64 (4x4 of 16x16 MFMA tiles).
// mode 0: outF fp32 = C + bias
// mode 1: outF fp32 = tanh(C + bias)
// mode 2: logits fp32 at [((row&31)*19 + (row>>5))*32000 + n] = C + bias
// mode 3: outB bf16 = C (no bias)
__global__ __launch_bounds__(256) void k_gemm_bt(const bf16* __restrict__ A,
                                                 const bf16* __restrict__ Bw,
                                                 const float* __restrict__ bias,
                                                 float* __restrict__ outF,
                                                 bf16* __restrict__ outB,
                                                 int M, int N, int K, int ldo,
                                                 int ntN, int mode) {
    int bx = blockIdx.x;
    int mt = bx / ntN, nt = bx % ntN;
    int tid = threadIdx.x, wv = tid >> 6, l = tid & 63;
    int m0 = mt * 128 + (wv >> 1) * 64;
    int n0 = nt * 128 + (wv & 1) * 64;
    int r = l & 15, ko = (l >> 4) * 8;

    const bf16* ap[4];
    const bf16* bp[4];
#pragma unroll
    for (int i = 0; i < 4; ++i) {
        int row = m0 + i * 16 + r;
        if (row > M - 1) row = M - 1;
        ap[i] = A + (size_t)row * K + ko;
    }
#pragma unroll
    for (int j = 0; j < 4; ++j) {
        int n = n0 + j * 16 + r;
        if (n > N - 1) n = N - 1;
        bp[j] = Bw + (size_t)n * K + ko;
    }

    f32x4 zv = {0.f, 0.f, 0.f, 0.f};
    f32x4 acc[4][4];
#pragma unroll
    for (int i = 0; i < 4; ++i)
#pragma unroll
        for (int j = 0; j < 4; ++j) acc[i][j] = zv;

    int nk = K >> 5;
    for (int kk = 0; kk < nk; ++kk) {
        bf16x8 af[4], bfv[4];
#pragma unroll
        for (int i = 0; i < 4; ++i) af[i] = ld8(ap[i] + kk * 32);
#pragma unroll
        for (int j = 0; j < 4; ++j) bfv[j] = ld8(bp[j] + kk * 32);
#pragma unroll
        for (int i = 0; i < 4; ++i)
#pragma unroll
            for (int j = 0; j < 4; ++j) acc[i][j] = MFMA(af[i], bfv[j], acc[i][j]);
    }

    int ccol = l & 15, cr = (l >> 4) * 4;
#pragma unroll
    for (int i = 0; i < 4; ++i) {
#pragma unroll
        for (int j = 0; j < 4; ++j) {
            int n = n0 + j * 16 + ccol;
            if (n >= N) continue;
            float bv = bias ? bias[n] : 0.f;
#pragma unroll
            for (int q = 0; q < 4; ++q) {
                int row = m0 + i * 16 + cr + q;
                if (row >= M) continue;
                float v = acc[i][j][q] + bv;
                if (mode == 1) v = tanhf(v);
                if (mode == 2) {
                    outF[((size_t)(row & 31) * 19 + (size_t)(row >> 5)) * 32000 + n] = v;
                } else if (mode == 3) {
                    outB[(size_t)row * ldo + n] = f2b(v);
                } else {
                    outF[(size_t)row * ldo + n] = v;
                }
            }
        }
    }
}

// ---------------------------------------------------------------------------
// Small-M GEMM: one 16x16 tile per block (64 threads = 1 wave).
__global__ __launch_bounds__(64) void k_gemm_sm(const bf16* __restrict__ A,
                                                const bf16* __restrict__ W,
                                                const float* __restrict__ bias,
                                                float* __restrict__ outF, int ldof,
                                                bf16* __restrict__ outB, int ldob,
                                                int K, int ntN, int act) {
    int bx = blockIdx.x;
    int mt = bx / ntN, nt = bx % ntN;
    int l = threadIdx.x;
    int r = l & 15, ko = (l >> 4) * 8;
    const bf16* ap = A + (size_t)(mt * 16 + r) * K + ko;
    const bf16* bp = W + (size_t)(nt * 16 + r) * K + ko;
    f32x4 acc = {0.f, 0.f, 0.f, 0.f};
    int nk = K >> 5;
#pragma unroll 4
    for (int kk = 0; kk < nk; ++kk) acc = MFMA(ld8(ap + kk * 32), ld8(bp + kk * 32), acc);
    int n = nt * 16 + (l & 15);
    int cr = (l >> 4) * 4;
    float bv = bias ? bias[n] : 0.f;
#pragma unroll
    for (int q = 0; q < 4; ++q) {
        int row = mt * 16 + cr + q;
        float v = acc[q] + bv;
        if (act == 1) v = fmaxf(v, 0.f);
        if (outF) outF[(size_t)row * ldof + n] = v;
        if (outB) outB[(size_t)row * ldob + n] = f2b(v);
    }
}

// ---------------------------------------------------------------------------
// Persistent cooperative encoder: ALL 128 LSTM steps in one kernel.
// Grid 64 blocks x 256 thr (4 waves = 4 gates). Each wave holds its 16 rows of
// Whh (j-slice of 16, one gate) as register B-fragments (128 VGPRs), loaded ONCE.
// Per step: A-frags stream from global double-buffered hb (64KB, L2-hot),
// fused pointwise with h/c state in registers, one grid.sync per step.
__global__ __launch_bounds__(256, 1) void k_enc_all(const bf16* __restrict__ Zx,
                                                    const bf16* __restrict__ Whh,
                                                    const float* __restrict__ bih,
                                                    const float* __restrict__ bhh,
                                                    const int* __restrict__ lens,
                                                    bf16* __restrict__ hb0,
                                                    bf16* __restrict__ hb1,
                                                    bf16* __restrict__ cbT,
                                                    bf16* __restrict__ SH) {
    cg::grid_group grid = cg::this_grid();
    __shared__ float zl[4][32][16];
    int j0 = blockIdx.x * 16;
    int tid = threadIdx.x;
    int g = tid >> 6, l = tid & 63;
    int r = l & 15, ko = (l >> 4) * 8;
    int n0 = g * 1024 + j0;

    // Load this wave's Whh slice into registers (16 rows x 1024 K), once.
    bf16x8 wreg[32];
    {
        const bf16* wp = Whh + (size_t)(n0 + r) * 1024 + ko;
#pragma unroll
        for (int kk = 0; kk < 32; ++kk) wreg[kk] = ld8(wp + kk * 32);
    }

    // Per-thread pointwise state: elements (b0, j) and (b1, j), j fixed.
    int b0 = tid >> 4, ji = tid & 15;
    int b1 = b0 + 16;
    int j = j0 + ji;
    float bs[4];
#pragma unroll
    for (int gg = 0; gg < 4; ++gg) bs[gg] = bih[gg * 1024 + j] + bhh[gg * 1024 + j];
    int len0 = lens[b0], len1 = lens[b1];
    float h0 = 0.f, c0 = 0.f, h1 = 0.f, c1 = 0.f;
    const bf16* zx0 = Zx + (size_t)(b0 * 128) * 4096 + j;
    const bf16* zx1 = Zx + (size_t)(b1 * 128) * 4096 + j;
    int ccol = l & 15, cr = (l >> 4) * 4;

    for (int t = 0; t < 128; ++t) {
        const bf16* hbcur = (t & 1) ? hb1 : hb0;
        bf16* hbnxt = (t & 1) ? hb0 : hb1;

        // z[g] slice = hb @ Whh[g-slice]^T
        const bf16* a0p = hbcur + (size_t)r * 1024 + ko;
        const bf16* a1p = hbcur + (size_t)(16 + r) * 1024 + ko;
        f32x4 acc0 = {0.f, 0.f, 0.f, 0.f}, acc1 = {0.f, 0.f, 0.f, 0.f};
#pragma unroll
        for (int kk = 0; kk < 32; ++kk) {
            acc0 = MFMA(ld8(a0p + kk * 32), wreg[kk], acc0);
            acc1 = MFMA(ld8(a1p + kk * 32), wreg[kk], acc1);
        }
#pragma unroll
        for (int q = 0; q < 4; ++q) {
            zl[g][cr + q][ccol] = acc0[q];
            zl[g][16 + cr + q][ccol] = acc1[q];
        }
        __syncthreads();

        // Fused pointwise: this thread owns (b0,j) and (b1,j).
        {
            float zi = zl[0][b0][ji] + b2f(zx0[(size_t)t * 4096])        + bs[0];
            float zf = zl[1][b0][ji] + b2f(zx0[(size_t)t * 4096 + 1024]) + bs[1];
            float zg = zl[2][b0][ji] + b2f(zx0[(size_t)t * 4096 + 2048]) + bs[2];
            float zo = zl[3][b0][ji] + b2f(zx0[(size_t)t * 4096 + 3072]) + bs[3];
            float cn = sigf(zf) * c0 + sigf(zi) * tanhf(zg);
            float hn = sigf(zo) * tanhf(cn);
            bool msk = t < len0;
            if (msk) { h0 = hn; c0 = cn; }
            hbnxt[b0 * 1024 + j] = f2b(h0);
            SH[((size_t)b0 * 128 + t) * 1024 + j] = msk ? f2b(hn) : f2b(0.f);
        }
        {
            float zi = zl[0][b1][ji] + b2f(zx1[(size_t)t * 4096])        + bs[0];
            float zf = zl[1][b1][ji] + b2f(zx1[(size_t)t * 4096 + 1024]) + bs[1];
            float zg = zl[2][b1][ji] + b2f(zx1[(size_t)t * 4096 + 2048]) + bs[2];
            float zo = zl[3][b1][ji] + b2f(zx1[(size_t)t * 4096 + 3072]) + bs[3];
            float cn = sigf(zf) * c1 + sigf(zi) * tanhf(zg);
            float hn = sigf(zo) * tanhf(cn);
            bool msk = t < len1;
            if (msk) { h1 = hn; c1 = cn; }
            hbnxt[b1 * 1024 + j] = f2b(h1);
            SH[((size_t)b1 * 128 + t) * 1024 + j] = msk ? f2b(hn) : f2b(0.f);
        }
        if (t == 127) {
            cbT[b0 * 1024 + j] = f2b(c0);
            cbT[b1 * 1024 + j] = f2b(c1);
        }
        __threadfence();
        grid.sync();
    }
}

// ---------------------------------------------------------------------------
// Decoder attention step. Grid 128 = 32 batches x 4 j-chunks (256 cols each).
// All chunks recompute a_key/energy/softmax (cheap); context read parallelized.
__global__ __launch_bounds__(256) void k_attn(const bf16* __restrict__ embedB,
                                              const int* __restrict__ trg,
                                              const float* __restrict__ akW,
                                              const float* __restrict__ akb,
                                              const float* __restrict__ qkB,
                                              const float* __restrict__ qvB,
                                              const int* __restrict__ lens,
                                              const float* __restrict__ hd,
                                              bf16* __restrict__ xin,
                                              bf16* __restrict__ featA, int t) {
    int b = blockIdx.x >> 2, chunk = blockIdx.x & 3;
    int tid = threadIdx.x;
    if (chunk == 0) {
        const unsigned int* er = (const unsigned int*)(embedB + (size_t)trg[b * 20 + t] * 512);
        ((unsigned int*)(xin + (size_t)b * 1536))[tid] = er[tid];
    }

    __shared__ float ak[100];
    __shared__ float part[256];
    __shared__ float ew[128];
    __shared__ float mxs, inv_s;

    float s = 0.f;
    if (tid < 200) {
        int n = tid >> 1, hh = tid & 1;
        const float* wr = akW + (size_t)n * 1024 + hh * 512;
        const float* hr = hd + (size_t)b * 1024 + hh * 512;
#pragma unroll 8
        for (int k = 0; k < 512; ++k) s += hr[k] * wr[k];
    }
    part[tid] = s;
    __syncthreads();
    if (tid < 100) ak[tid] = tanhf(part[2 * tid] + part[2 * tid + 1] + akb[tid]);
    __syncthreads();

    if (tid < 128) {
        const float* qr = qkB + ((size_t)b * 128 + tid) * 100;
        float e = 0.f;
#pragma unroll 4
        for (int k = 0; k < 100; ++k) e += qr[k] * ak[k];
        ew[tid] = (tid < lens[b]) ? e : -INFINITY;
    }
    __syncthreads();
    if (tid == 0) {
        float m = ew[0];
        for (int s2 = 1; s2 < 128; ++s2) m = fmaxf(m, ew[s2]);
        mxs = m;
    }
    __syncthreads();
    if (tid < 128) ew[tid] = expf(ew[tid] - mxs);
    __syncthreads();
    if (tid == 0) {
        float sm = 0.f;
        for (int s2 = 0; s2 < 128; ++s2) sm += ew[s2];
        inv_s = 1.0f / sm;
    }
    __syncthreads();

    // context slice: 256 cols per chunk, one col per thread
    {
        int j = (chunk << 8) + tid;
        const float* qvb = qvB + ((size_t)b * 128) * 1024 + j;
        float a0 = 0.f;
#pragma unroll 4
        for (int s2 = 0; s2 < 128; ++s2) a0 += ew[s2] * qvb[(size_t)s2 * 1024];
        a0 *= inv_s;
        bf16 cb = f2b(a0);
        xin[(size_t)b * 1536 + 512 + j] = cb;
        featA[(size_t)b * 2048 + 1024 + j] = cb;
    }
}

// ---------------------------------------------------------------------------
// Decoder LSTM step. Grid 256 blocks x 64 thr (1 wave). Each block: j-slice of 4,
// with 4 gates x 4 cols packed into one 16-row MFMA N-tile.
__global__ __launch_bounds__(64) void k_dec_z(const bf16* __restrict__ xin,
                                              const bf16* __restrict__ Wih,
                                              const bf16* __restrict__ hb_in,
                                              const bf16* __restrict__ Whh,
                                              const float* __restrict__ bih,
                                              const float* __restrict__ bhh,
                                              float* __restrict__ hd,
                                              float* __restrict__ cd,
                                              bf16* __restrict__ hb_out,
                                              bf16* __restrict__ featA) {
    __shared__ float zl[32][16];
    int j0 = blockIdx.x * 4;
    int l = threadIdx.x;
    int r = l & 15, ko = (l >> 4) * 8;
    int wrow = (r >> 2) * 1024 + j0 + (r & 3);  // packed (gate, ji) -> Whh/Wih row

    f32x4 acc0 = {0.f, 0.f, 0.f, 0.f}, acc1 = {0.f, 0.f, 0.f, 0.f};
    {
        const bf16* a0 = xin + (size_t)r * 1536 + ko;
        const bf16* a1 = xin + (size_t)(16 + r) * 1536 + ko;
        const bf16* bp = Wih + (size_t)wrow * 1536 + ko;
#pragma unroll 4
        for (int kk = 0; kk < 48; ++kk) {
            bf16x8 bv = ld8(bp + kk * 32);
            acc0 = MFMA(ld8(a0 + kk * 32), bv, acc0);
            acc1 = MFMA(ld8(a1 + kk * 32), bv, acc1);
        }
    }
    {
        const bf16* a0 = hb_in + (size_t)r * 1024 + ko;
        const bf16* a1 = hb_in + (size_t)(16 + r) * 1024 + ko;
        const bf16* bp = Whh + (size_t)wrow * 1024 + ko;
#pragma unroll 4
        for (int kk = 0; kk < 32; ++kk) {
            bf16x8 bv = ld8(bp + kk * 32);
            acc0 = MFMA(ld8(a0 + kk * 32), bv, acc0);
            acc1 = MFMA(ld8(a1 + kk * 32), bv, acc1);
        }
    }
    int ccol = l & 15, cr = (l >> 4) * 4;
#pragma unroll
    for (int q = 0; q < 4; ++q) {
        zl[cr + q][ccol] = acc0[q];
        zl[16 + cr + q][ccol] = acc1[q];
    }
    __syncthreads();

    // pointwise: 128 elems (32 b x 4 cols), 2 per thread
#pragma unroll
    for (int e = l; e < 128; e += 64) {
        int b = e >> 2, jj = e & 3;
        int j = j0 + jj;
        float zi = zl[b][jj]      + bih[j]        + bhh[j];
        float zf = zl[b][4 + jj]  + bih[1024 + j] + bhh[1024 + j];
        float zg = zl[b][8 + jj]  + bih[2048 + j] + bhh[2048 + j];
        float zo = zl[b][12 + jj] + bih[3072 + j] + bhh[3072 + j];
        int hi = b * 1024 + j;
        float co = cd[hi];
        float cn = sigf(zf) * co + sigf(zi) * tanhf(zg);
        float hn = sigf(zo) * tanhf(cn);
        hd[hi] = hn;
        cd[hi] = cn;
        hb_out[hi] = f2b(hn);
        featA[(size_t)b * 2048 + j] = f2b(hn);
    }
}

// ---------------------------------------------------------------------------
extern "C" void kernel_launch(void* const* d_in, const int* in_sizes, int n_in,
                              void* d_out, int out_size, void* d_ws, size_t ws_size,
                              hipStream_t stream) {
    const float* embed   = (const float*)d_in[0];
    const float* enc_Wih = (const float*)d_in[1];
    const float* enc_Whh = (const float*)d_in[2];
    const float* enc_bih = (const float*)d_in[3];
    const float* enc_bhh = (const float*)d_in[4];
    const float* dec_Wih = (const float*)d_in[5];
    const float* dec_Whh = (const float*)d_in[6];
    const float* dec_bih = (const float*)d_in[7];
    const float* dec_bhh = (const float*)d_in[8];
    const float* qk_W    = (const float*)d_in[9];
    const float* qk_b    = (const float*)d_in[10];
    const float* qv_W    = (const float*)d_in[11];
    const float* qv_b    = (const float*)d_in[12];
    const float* ak_W    = (const float*)d_in[13];
    const float* ak_b    = (const float*)d_in[14];
    const float* out_W   = (const float*)d_in[15];
    const float* out_b   = (const float*)d_in[16];
    const float* wd_b    = (const float*)d_in[17];
    const float* hfc1_W  = (const float*)d_in[18];
    const float* hfc1_b  = (const float*)d_in[19];
    const float* hfc2_W  = (const float*)d_in[20];
    const float* hfc2_b  = (const float*)d_in[21];
    const float* cfc1_W  = (const float*)d_in[22];
    const float* cfc1_b  = (const float*)d_in[23];
    const float* cfc2_W  = (const float*)d_in[24];
    const float* cfc2_b  = (const float*)d_in[25];
    const int* src  = (const int*)d_in[26];
    const int* lens = (const int*)d_in[27];
    const int* trg  = (const int*)d_in[28];

    char* cur = (char*)d_ws;
    auto alloc = [&](size_t bytes) -> char* {
        char* p = cur;
        cur += (bytes + 255) & ~(size_t)255;
        return p;
    };
    bf16* embedB  = (bf16*)alloc((size_t)16384000 * 2);
    bf16* encWihB = (bf16*)alloc((size_t)2097152 * 2);
    bf16* encWhhB = (bf16*)alloc((size_t)4194304 * 2);
    bf16* decWihB = (bf16*)alloc((size_t)6291456 * 2);
    bf16* decWhhB = (bf16*)alloc((size_t)4194304 * 2);
    bf16* qkWB    = (bf16*)alloc((size_t)102400 * 2);
    bf16* qvWB    = (bf16*)alloc((size_t)1048576 * 2);
    bf16* outWB   = (bf16*)alloc((size_t)1048576 * 2);
    bf16* hfc1B   = (bf16*)alloc((size_t)2097152 * 2);
    bf16* hfc2B   = (bf16*)alloc((size_t)2097152 * 2);
    bf16* cfc1B   = (bf16*)alloc((size_t)2097152 * 2);
    bf16* cfc2B   = (bf16*)alloc((size_t)2097152 * 2);
    bf16*  Xsrc  = (bf16*)alloc((size_t)4096 * 512 * 2);
    bf16*  Zx    = (bf16*)alloc((size_t)4096 * 4096 * 2);
    bf16*  SH    = (bf16*)alloc((size_t)4096 * 1024 * 2);
    float* qkB   = (float*)alloc((size_t)4096 * 100 * 4);
    float* qvB   = (float*)alloc((size_t)4096 * 1024 * 4);
    bf16*  hbA   = (bf16*)alloc(32 * 1024 * 2);
    bf16*  hbB   = (bf16*)alloc(32 * 1024 * 2);
    bf16*  cbT   = (bf16*)alloc(32 * 1024 * 2);
    bf16*  t1    = (bf16*)alloc(32 * 2048 * 2);
    float* hd    = (float*)alloc(32 * 1024 * 4);
    float* cd    = (float*)alloc(32 * 1024 * 4);
    bf16*  hdA   = (bf16*)alloc(32 * 1024 * 2);
    bf16*  hdB   = (bf16*)alloc(32 * 1024 * 2);
    bf16*  xin   = (bf16*)alloc(32 * 1536 * 2);
    bf16*  featA = (bf16*)alloc(32 * 2048 * 2);
    bf16*  feats = (bf16*)alloc((size_t)608 * 512 * 2);
    if ((size_t)(cur - (char*)d_ws) > ws_size) return;  // workspace too small

    hipMemsetAsync(hbA, 0, 32 * 1024 * 2, stream);

    ConvTable tab;
    tab.d[0]  = {embed,   embedB,  16384000};
    tab.d[1]  = {enc_Wih, encWihB, 2097152};
    tab.d[2]  = {enc_Whh, encWhhB, 4194304};
    tab.d[3]  = {dec_Wih, decWihB, 6291456};
    tab.d[4]  = {dec_Whh, decWhhB, 4194304};
    tab.d[5]  = {qk_W,    qkWB,    102400};
    tab.d[6]  = {qv_W,    qvWB,    1048576};
    tab.d[7]  = {out_W,   outWB,   1048576};
    tab.d[8]  = {hfc1_W,  hfc1B,   2097152};
    tab.d[9]  = {hfc2_W,  hfc2B,   2097152};
    tab.d[10] = {cfc1_W,  cfc1B,   2097152};
    tab.d[11] = {cfc2_W,  cfc2B,   2097152};
    k_conv<<<dim3(1024, 12), 256, 0, stream>>>(tab);

    k_gather<<<4096, 256, 0, stream>>>((const unsigned int*)embedB, src, (unsigned int*)Xsrc);

    // Zx = Xsrc @ enc_Wih^T  (M=4096, N=4096, K=512), bf16 out
    k_gemm_bt<<<32 * 32, 256, 0, stream>>>(Xsrc, encWihB, nullptr, nullptr, Zx,
                                           4096, 4096, 512, 4096, 32, 3);

    // Persistent cooperative encoder: all 128 steps, one launch.
    {
        const bf16* ZxA = Zx;  const bf16* WhhA = encWhhB;
        const float* bihA = enc_bih; const float* bhhA = enc_bhh;
        const int* lensA = lens;
        bf16* hb0A = hbA; bf16* hb1A = hbB; bf16* cbTA = cbT; bf16* SHA = SH;
        void* args[] = {(void*)&ZxA, (void*)&WhhA, (void*)&bihA, (void*)&bhhA,
                        (void*)&lensA, (void*)&hb0A, (void*)&hb1A, (void*)&cbTA,
                        (void*)&SHA};
        hipLaunchCooperativeKernel((void*)k_enc_all, dim3(64), dim3(256), args, 0, stream);
    }
    bf16* hbT = hbA;  // buffer written at t=127 ((127&1)^1 == 0)

    k_gemm_sm<<<256, 64, 0, stream>>>(hbT, hfc1B, hfc1_b, nullptr, 0, t1, 2048, 1024, 128, 1);
    k_gemm_sm<<<128, 64, 0, stream>>>(t1, hfc2B, hfc2_b, hd, 1024, hdA, 1024, 2048, 64, 0);
    k_gemm_sm<<<256, 64, 0, stream>>>(cbT, cfc1B, cfc1_b, nullptr, 0, t1, 2048, 1024, 128, 1);
    k_gemm_sm<<<128, 64, 0, stream>>>(t1, cfc2B, cfc2_b, cd, 1024, nullptr, 0, 2048, 64, 0);

    k_gemm_bt<<<32, 256, 0, stream>>>(SH, qkWB, qk_b, qkB, nullptr,
                                      4096, 100, 1024, 100, 1, 1);
    k_gemm_bt<<<256, 256, 0, stream>>>(SH, qvWB, qv_b, qvB, nullptr,
                                       4096, 1024, 1024, 1024, 8, 0);

    for (int t = 0; t < 19; ++t) {
        const bf16* hin = (t & 1) ? hdB : hdA;
        bf16* hout = (t & 1) ? hdA : hdB;
        k_attn<<<128, 256, 0, stream>>>(embedB, trg, ak_W, ak_b, qkB, qvB, lens, hd,
                                        xin, featA, t);
        k_dec_z<<<256, 64, 0, stream>>>(xin, decWihB, hin, decWhhB, dec_bih, dec_bhh,
                                        hd, cd, hout, featA);
        k_gemm_sm<<<64, 64, 0, stream>>>(featA, outWB, out_b, nullptr, 0,
                                         feats + (size_t)t * 32 * 512, 512, 2048, 32, 0);
    }

    k_gemm_bt<<<5 * 250, 256, 0, stream>>>(feats, embedB, wd_b, (float*)d_out, nullptr,
                                           608, 32000, 512, 0, 250, 2);
}

// Round 4
// 4520.208 us; speedup vs baseline: 1.0824x; 1.0824x over previous
//
#include <hip/hip_runtime.h>
#include <hip/hip_bf16.h>

// Problem constants: B=32, S=128, T=20 (19 dec steps), H=1024, D=512, K_attn=100, V=32000
// Inputs float32; output d_out float32 (B,19,V).
// bf16 MFMA with fp32 accumulate; recurrent state fp32 in registers.
// Encoder: persistent cooperative kernel, cross-block h exchange via agent-scope
// (sc1/LLC) atomics + flag barrier — NO grid.sync, NO threadfence (no L2 wb/inv).

using bf16 = __hip_bfloat16;
typedef __attribute__((ext_vector_type(8))) __bf16 bf16x8;
typedef __attribute__((ext_vector_type(4))) float f32x4;

__device__ __forceinline__ bf16x8 ld8(const bf16* p) {
    return *reinterpret_cast<const bf16x8*>(p);
}
__device__ __forceinline__ float b2f(bf16 v) { return __bfloat162float(v); }
__device__ __forceinline__ bf16 f2b(float v) { return __float2bfloat16(v); }
__device__ __forceinline__ unsigned short b2u(bf16 v) {
    unsigned short u; __builtin_memcpy(&u, &v, 2); return u;
}
__device__ __forceinline__ float sigf(float x) { return 1.0f / (1.0f + expf(-x)); }

#define MFMA(a, b, c) __builtin_amdgcn_mfma_f32_16x16x32_bf16((a), (b), (c), 0, 0, 0)

// ---------------------------------------------------------------------------
// f32 -> bf16 conversion for weight tensors. blockIdx.y selects tensor.
struct ConvDesc { const float* src; bf16* dst; int n; };
struct ConvTable { ConvDesc d[12]; };

__global__ __launch_bounds__(256) void k_conv(ConvTable tab) {
    ConvDesc cd = tab.d[blockIdx.y];
    int stride = gridDim.x * blockDim.x * 4;
    for (int i = (blockIdx.x * blockDim.x + threadIdx.x) * 4; i < cd.n; i += stride) {
        float4 v = *reinterpret_cast<const float4*>(cd.src + i);
        bf16 tmp[4] = {f2b(v.x), f2b(v.y), f2b(v.z), f2b(v.w)};
        *reinterpret_cast<ushort4*>(cd.dst + i) = *reinterpret_cast<const ushort4*>(tmp);
    }
}

// ---------------------------------------------------------------------------
// Gather bf16 embedding rows (512 bf16 = 256 u32 per row), one block per row.
__global__ __launch_bounds__(256) void k_gather(const unsigned int* __restrict__ table,
                                                const int* __restrict__ idx,
                                                unsigned int* __restrict__ out) {
    int r = blockIdx.x;
    out[(size_t)r * 256 + threadIdx.x] = table[(size_t)idx[r] * 256 + threadIdx.x];
}

// ---------------------------------------------------------------------------
// Generic big tiled GEMM: C = A(MxK) @ Bw(NxK)^T  (both row-major, bf16)
// mode 0: outF fp32 = C + bias ; mode 1: tanh ; mode 2: logits remap ; mode 3: bf16
__global__ __launch_bounds__(256) void k_gemm_bt(const bf16* __restrict__ A,
                                                 const bf16* __restrict__ Bw,
                                                 const float* __restrict__ bias,
                                                 float* __restrict__ outF,
                                                 bf16* __restrict__ outB,
                                                 int M, int N, int K, int ldo,
                                                 int ntN, int mode) {
    int bx = blockIdx.x;
    int mt = bx / ntN, nt = bx % ntN;
    int tid = threadIdx.x, wv = tid >> 6, l = tid & 63;
    int m0 = mt * 128 + (wv >> 1) * 64;
    int n0 = nt * 128 + (wv & 1) * 64;
    int r = l & 15, ko = (l >> 4) * 8;

    const bf16* ap[4];
    const bf16* bp[4];
#pragma unroll
    for (int i = 0; i < 4; ++i) {
        int row = m0 + i * 16 + r;
        if (row > M - 1) row = M - 1;
        ap[i] = A + (size_t)row * K + ko;
    }
#pragma unroll
    for (int j = 0; j < 4; ++j) {
        int n = n0 + j * 16 + r;
        if (n > N - 1) n = N - 1;
        bp[j] = Bw + (size_t)n * K + ko;
    }

    f32x4 zv = {0.f, 0.f, 0.f, 0.f};
    f32x4 acc[4][4];
#pragma unroll
    for (int i = 0; i < 4; ++i)
#pragma unroll
        for (int j = 0; j < 4; ++j) acc[i][j] = zv;

    int nk = K >> 5;
    for (int kk = 0; kk < nk; ++kk) {
        bf16x8 af[4], bfv[4];
#pragma unroll
        for (int i = 0; i < 4; ++i) af[i] = ld8(ap[i] + kk * 32);
#pragma unroll
        for (int j = 0; j < 4; ++j) bfv[j] = ld8(bp[j] + kk * 32);
#pragma unroll
        for (int i = 0; i < 4; ++i)
#pragma unroll
            for (int j = 0; j < 4; ++j) acc[i][j] = MFMA(af[i], bfv[j], acc[i][j]);
    }

    int ccol = l & 15, cr = (l >> 4) * 4;
#pragma unroll
    for (int i = 0; i < 4; ++i) {
#pragma unroll
        for (int j = 0; j < 4; ++j) {
            int n = n0 + j * 16 + ccol;
            if (n >= N) continue;
            float bv = bias ? bias[n] : 0.f;
#pragma unroll
            for (int q = 0; q < 4; ++q) {
                int row = m0 + i * 16 + cr + q;
                if (row >= M) continue;
                float v = acc[i][j][q] + bv;
                if (mode == 1) v = tanhf(v);
                if (mode == 2) {
                    outF[((size_t)(row & 31) * 19 + (size_t)(row >> 5)) * 32000 + n] = v;
                } else if (mode == 3) {
                    outB[(size_t)row * ldo + n] = f2b(v);
                } else {
                    outF[(size_t)row * ldo + n] = v;
                }
            }
        }
    }
}

// ---------------------------------------------------------------------------
// Small-M GEMM: one 16x16 tile per block (64 threads = 1 wave).
__global__ __launch_bounds__(64) void k_gemm_sm(const bf16* __restrict__ A,
                                                const bf16* __restrict__ W,
                                                const float* __restrict__ bias,
                                                float* __restrict__ outF, int ldof,
                                                bf16* __restrict__ outB, int ldob,
                                                int K, int ntN, int act) {
    int bx = blockIdx.x;
    int mt = bx / ntN, nt = bx % ntN;
    int l = threadIdx.x;
    int r = l & 15, ko = (l >> 4) * 8;
    const bf16* ap = A + (size_t)(mt * 16 + r) * K + ko;
    const bf16* bp = W + (size_t)(nt * 16 + r) * K + ko;
    f32x4 acc = {0.f, 0.f, 0.f, 0.f};
    int nk = K >> 5;
#pragma unroll 4
    for (int kk = 0; kk < nk; ++kk) acc = MFMA(ld8(ap + kk * 32), ld8(bp + kk * 32), acc);
    int n = nt * 16 + (l & 15);
    int cr = (l >> 4) * 4;
    float bv = bias ? bias[n] : 0.f;
#pragma unroll
    for (int q = 0; q < 4; ++q) {
        int row = mt * 16 + cr + q;
        float v = acc[q] + bv;
        if (act == 1) v = fmaxf(v, 0.f);
        if (outF) outF[(size_t)row * ldof + n] = v;
        if (outB) outB[(size_t)row * ldob + n] = f2b(v);
    }
}

// ---------------------------------------------------------------------------
// Persistent encoder, 128 LSTM steps, custom LLC barrier (no grid.sync).
// Grid 64 blocks x 256 thr (4 waves = 4 gates). Whh j-slice in VGPRs (loaded once).
// Per step: stage h (64KB) from LLC via sc1 atomics -> LDS (XOR-swizzled),
// MFMA from LDS x wreg, fused pointwise (state in regs), publish h slice via
// sc1 atomic stores, one release atomicAdd + relaxed spin per block.
__global__ __launch_bounds__(256, 1) void k_enc_all(const bf16* __restrict__ Zx,
                                                    const bf16* __restrict__ Whh,
                                                    const float* __restrict__ bih,
                                                    const float* __restrict__ bhh,
                                                    const int* __restrict__ lens,
                                                    unsigned int* __restrict__ hbw0,
                                                    unsigned int* __restrict__ hbw1,
                                                    bf16* __restrict__ cbT,
                                                    bf16* __restrict__ SH,
                                                    int* __restrict__ bar) {
    __shared__ bf16 hlds[32][1024];          // 64KB staged h, XOR-swizzled 16B units
    __shared__ float zl[4][32][16];          // 8KB gate outputs
    __shared__ unsigned short hpub[32][16];  // 1KB publish staging
    unsigned int* hldsw = (unsigned int*)hlds;
    const bf16x8* hldsv = (const bf16x8*)hlds;

    int j0 = blockIdx.x * 16;
    int tid = threadIdx.x;
    int g = tid >> 6, l = tid & 63;
    int r = l & 15, ko = (l >> 4) * 8;

    // Whh slice -> registers (16 rows x 1024 K per wave), loaded once.
    bf16x8 wreg[32];
    {
        const bf16* wp = Whh + (size_t)(g * 1024 + j0 + r) * 1024 + ko;
#pragma unroll
        for (int kk = 0; kk < 32; ++kk) wreg[kk] = ld8(wp + kk * 32);
    }

    int b0 = tid >> 4, ji = tid & 15;
    int b1 = b0 + 16;
    int j = j0 + ji;
    float bs[4];
#pragma unroll
    for (int gg = 0; gg < 4; ++gg) bs[gg] = bih[gg * 1024 + j] + bhh[gg * 1024 + j];
    int len0 = lens[b0], len1 = lens[b1];
    float h0 = 0.f, c0 = 0.f, h1 = 0.f, c1 = 0.f;
    const bf16* zx0 = Zx + (size_t)(b0 * 128) * 4096 + j;
    const bf16* zx1 = Zx + (size_t)(b1 * 128) * 4096 + j;
    int ccol = l & 15, cr = (l >> 4) * 4;
    int rk = r & 7;  // XOR swizzle key (same for rows r and r+16)

    for (int t = 0; t < 128; ++t) {
        // Prefetch Zx[t] (independent of barrier) — hides LLC latency under spin.
        float za0[4], za1[4];
#pragma unroll
        for (int gg = 0; gg < 4; ++gg) {
            za0[gg] = b2f(zx0[(size_t)t * 4096 + gg * 1024]);
            za1[gg] = b2f(zx1[(size_t)t * 4096 + gg * 1024]);
        }

        // Wait for all producers of h_t (t=0: initial zeros from memset).
        if (t > 0) {
            if (tid == 0) {
                while (__hip_atomic_load(bar + (t - 1), __ATOMIC_RELAXED,
                                         __HIP_MEMORY_SCOPE_AGENT) < 64)
                    __builtin_amdgcn_s_sleep(1);
                (void)__hip_atomic_load(bar + (t - 1), __ATOMIC_ACQUIRE,
                                        __HIP_MEMORY_SCOPE_AGENT);
            }
            __syncthreads();
        }

        // Stage h_t (64KB) LLC -> LDS, swizzled: unit u -> u ^ (row & 7).
        const unsigned int* hw = (t & 1) ? hbw1 : hbw0;
#pragma unroll 4
        for (int i = 0; i < 64; ++i) {
            int d = i * 256 + tid;
            int b = d >> 9, w = d & 511;
            unsigned int v = __hip_atomic_load(hw + d, __ATOMIC_RELAXED,
                                               __HIP_MEMORY_SCOPE_AGENT);
            hldsw[b * 512 + ((((w >> 2) ^ (b & 7)) << 2) | (w & 3))] = v;
        }
        __syncthreads();

        // z[g] slice = h @ Whh[g-slice]^T from LDS.
        f32x4 acc0 = {0.f, 0.f, 0.f, 0.f}, acc1 = {0.f, 0.f, 0.f, 0.f};
#pragma unroll
        for (int kk = 0; kk < 32; ++kk) {
            int u = kk * 4 + (l >> 4);
            acc0 = MFMA(hldsv[r * 128 + (u ^ rk)], wreg[kk], acc0);
            acc1 = MFMA(hldsv[(16 + r) * 128 + (u ^ rk)], wreg[kk], acc1);
        }
#pragma unroll
        for (int q = 0; q < 4; ++q) {
            zl[g][cr + q][ccol] = acc0[q];
            zl[g][16 + cr + q][ccol] = acc1[q];
        }
        __syncthreads();

        // Fused pointwise: this thread owns (b0,j) and (b1,j).
        {
            float zi = zl[0][b0][ji] + za0[0] + bs[0];
            float zf = zl[1][b0][ji] + za0[1] + bs[1];
            float zg = zl[2][b0][ji] + za0[2] + bs[2];
            float zo = zl[3][b0][ji] + za0[3] + bs[3];
            float cn = sigf(zf) * c0 + sigf(zi) * tanhf(zg);
            float hn = sigf(zo) * tanhf(cn);
            bool msk = t < len0;
            if (msk) { h0 = hn; c0 = cn; }
            hpub[b0][ji] = b2u(f2b(h0));
            SH[((size_t)b0 * 128 + t) * 1024 + j] = msk ? f2b(hn) : f2b(0.f);
        }
        {
            float zi = zl[0][b1][ji] + za1[0] + bs[0];
            float zf = zl[1][b1][ji] + za1[1] + bs[1];
            float zg = zl[2][b1][ji] + za1[2] + bs[2];
            float zo = zl[3][b1][ji] + za1[3] + bs[3];
            float cn = sigf(zf) * c1 + sigf(zi) * tanhf(zg);
            float hn = sigf(zo) * tanhf(cn);
            bool msk = t < len1;
            if (msk) { h1 = hn; c1 = cn; }
            hpub[b1][ji] = b2u(f2b(h1));
            SH[((size_t)b1 * 128 + t) * 1024 + j] = msk ? f2b(hn) : f2b(0.f);
        }
        if (t == 127) {
            cbT[b0 * 1024 + j] = f2b(c0);
            cbT[b1 * 1024 + j] = f2b(c1);
        }
        __syncthreads();

        // Publish this block's h_{t+1} slice (32 b x 16 j = 256 u32) to LLC.
        unsigned int* hwn = (t & 1) ? hbw0 : hbw1;
        {
            int pb = tid >> 3, pw = tid & 7;
            unsigned int val = (unsigned int)hpub[pb][2 * pw] |
                               ((unsigned int)hpub[pb][2 * pw + 1] << 16);
            __hip_atomic_store(hwn + (size_t)pb * 512 + (j0 >> 1) + pw, val,
                               __ATOMIC_RELAXED, __HIP_MEMORY_SCOPE_AGENT);
        }
        __syncthreads();  // drains vmcnt for all waves' sc1 stores
        if (tid == 0)
            __hip_atomic_fetch_add(bar + t, 1, __ATOMIC_RELEASE,
                                   __HIP_MEMORY_SCOPE_AGENT);
    }
}

// ---------------------------------------------------------------------------
// Decoder attention step. Grid 128 = 32 batches x 4 j-chunks (256 cols each).
__global__ __launch_bounds__(256) void k_attn(const bf16* __restrict__ embedB,
                                              const int* __restrict__ trg,
                                              const float* __restrict__ akW,
                                              const float* __restrict__ akb,
                                              const float* __restrict__ qkB,
                                              const float* __restrict__ qvB,
                                              const int* __restrict__ lens,
                                              const float* __restrict__ hd,
                                              bf16* __restrict__ xin,
                                              bf16* __restrict__ featA, int t) {
    int b = blockIdx.x >> 2, chunk = blockIdx.x & 3;
    int tid = threadIdx.x;
    if (chunk == 0) {
        const unsigned int* er = (const unsigned int*)(embedB + (size_t)trg[b * 20 + t] * 512);
        ((unsigned int*)(xin + (size_t)b * 1536))[tid] = er[tid];
    }

    __shared__ float ak[100];
    __shared__ float part[256];
    __shared__ float ew[128];
    __shared__ float mxs, inv_s;

    float s = 0.f;
    if (tid < 200) {
        int n = tid >> 1, hh = tid & 1;
        const float* wr = akW + (size_t)n * 1024 + hh * 512;
        const float* hr = hd + (size_t)b * 1024 + hh * 512;
#pragma unroll 8
        for (int k = 0; k < 512; ++k) s += hr[k] * wr[k];
    }
    part[tid] = s;
    __syncthreads();
    if (tid < 100) ak[tid] = tanhf(part[2 * tid] + part[2 * tid + 1] + akb[tid]);
    __syncthreads();

    if (tid < 128) {
        const float* qr = qkB + ((size_t)b * 128 + tid) * 100;
        float e = 0.f;
#pragma unroll 4
        for (int k = 0; k < 100; ++k) e += qr[k] * ak[k];
        ew[tid] = (tid < lens[b]) ? e : -INFINITY;
    }
    __syncthreads();
    if (tid == 0) {
        float m = ew[0];
        for (int s2 = 1; s2 < 128; ++s2) m = fmaxf(m, ew[s2]);
        mxs = m;
    }
    __syncthreads();
    if (tid < 128) ew[tid] = expf(ew[tid] - mxs);
    __syncthreads();
    if (tid == 0) {
        float sm = 0.f;
        for (int s2 = 0; s2 < 128; ++s2) sm += ew[s2];
        inv_s = 1.0f / sm;
    }
    __syncthreads();

    {
        int jj = (chunk << 8) + tid;
        const float* qvb = qvB + ((size_t)b * 128) * 1024 + jj;
        float a0 = 0.f;
#pragma unroll 4
        for (int s2 = 0; s2 < 128; ++s2) a0 += ew[s2] * qvb[(size_t)s2 * 1024];
        a0 *= inv_s;
        bf16 cb = f2b(a0);
        xin[(size_t)b * 1536 + 512 + jj] = cb;
        featA[(size_t)b * 2048 + 1024 + jj] = cb;
    }
}

// ---------------------------------------------------------------------------
// Decoder LSTM step. Grid 256 blocks x 64 thr; gates x 4 j packed in N-tile.
__global__ __launch_bounds__(64) void k_dec_z(const bf16* __restrict__ xin,
                                              const bf16* __restrict__ Wih,
                                              const bf16* __restrict__ hb_in,
                                              const bf16* __restrict__ Whh,
                                              const float* __restrict__ bih,
                                              const float* __restrict__ bhh,
                                              float* __restrict__ hd,
                                              float* __restrict__ cd,
                                              bf16* __restrict__ hb_out,
                                              bf16* __restrict__ featA) {
    __shared__ float zl[32][16];
    int j0 = blockIdx.x * 4;
    int l = threadIdx.x;
    int r = l & 15, ko = (l >> 4) * 8;
    int wrow = (r >> 2) * 1024 + j0 + (r & 3);

    f32x4 acc0 = {0.f, 0.f, 0.f, 0.f}, acc1 = {0.f, 0.f, 0.f, 0.f};
    {
        const bf16* a0 = xin + (size_t)r * 1536 + ko;
        const bf16* a1 = xin + (size_t)(16 + r) * 1536 + ko;
        const bf16* bp = Wih + (size_t)wrow * 1536 + ko;
#pragma unroll 4
        for (int kk = 0; kk < 48; ++kk) {
            bf16x8 bv = ld8(bp + kk * 32);
            acc0 = MFMA(ld8(a0 + kk * 32), bv, acc0);
            acc1 = MFMA(ld8(a1 + kk * 32), bv, acc1);
        }
    }
    {
        const bf16* a0 = hb_in + (size_t)r * 1024 + ko;
        const bf16* a1 = hb_in + (size_t)(16 + r) * 1024 + ko;
        const bf16* bp = Whh + (size_t)wrow * 1024 + ko;
#pragma unroll 4
        for (int kk = 0; kk < 32; ++kk) {
            bf16x8 bv = ld8(bp + kk * 32);
            acc0 = MFMA(ld8(a0 + kk * 32), bv, acc0);
            acc1 = MFMA(ld8(a1 + kk * 32), bv, acc1);
        }
    }
    int ccol = l & 15, cr = (l >> 4) * 4;
#pragma unroll
    for (int q = 0; q < 4; ++q) {
        zl[cr + q][ccol] = acc0[q];
        zl[16 + cr + q][ccol] = acc1[q];
    }
    __syncthreads();

#pragma unroll
    for (int e = l; e < 128; e += 64) {
        int b = e >> 2, jj = e & 3;
        int j = j0 + jj;
        float zi = zl[b][jj]      + bih[j]        + bhh[j];
        float zf = zl[b][4 + jj]  + bih[1024 + j] + bhh[1024 + j];
        float zg = zl[b][8 + jj]  + bih[2048 + j] + bhh[2048 + j];
        float zo = zl[b][12 + jj] + bih[3072 + j] + bhh[3072 + j];
        int hi = b * 1024 + j;
        float co = cd[hi];
        float cn = sigf(zf) * co + sigf(zi) * tanhf(zg);
        float hn = sigf(zo) * tanhf(cn);
        hd[hi] = hn;
        cd[hi] = cn;
        hb_out[hi] = f2b(hn);
        featA[(size_t)b * 2048 + j] = f2b(hn);
    }
}

// ---------------------------------------------------------------------------
extern "C" void kernel_launch(void* const* d_in, const int* in_sizes, int n_in,
                              void* d_out, int out_size, void* d_ws, size_t ws_size,
                              hipStream_t stream) {
    const float* embed   = (const float*)d_in[0];
    const float* enc_Wih = (const float*)d_in[1];
    const float* enc_Whh = (const float*)d_in[2];
    const float* enc_bih = (const float*)d_in[3];
    const float* enc_bhh = (const float*)d_in[4];
    const float* dec_Wih = (const float*)d_in[5];
    const float* dec_Whh = (const float*)d_in[6];
    const float* dec_bih = (const float*)d_in[7];
    const float* dec_bhh = (const float*)d_in[8];
    const float* qk_W    = (const float*)d_in[9];
    const float* qk_b    = (const float*)d_in[10];
    const float* qv_W    = (const float*)d_in[11];
    const float* qv_b    = (const float*)d_in[12];
    const float* ak_W    = (const float*)d_in[13];
    const float* ak_b    = (const float*)d_in[14];
    const float* out_W   = (const float*)d_in[15];
    const float* out_b   = (const float*)d_in[16];
    const float* wd_b    = (const float*)d_in[17];
    const float* hfc1_W  = (const float*)d_in[18];
    const float* hfc1_b  = (const float*)d_in[19];
    const float* hfc2_W  = (const float*)d_in[20];
    const float* hfc2_b  = (const float*)d_in[21];
    const float* cfc1_W  = (const float*)d_in[22];
    const float* cfc1_b  = (const float*)d_in[23];
    const float* cfc2_W  = (const float*)d_in[24];
    const float* cfc2_b  = (const float*)d_in[25];
    const int* src  = (const int*)d_in[26];
    const int* lens = (const int*)d_in[27];
    const int* trg  = (const int*)d_in[28];

    char* cur = (char*)d_ws;
    auto alloc = [&](size_t bytes) -> char* {
        char* p = cur;
        cur += (bytes + 255) & ~(size_t)255;
        return p;
    };
    bf16* embedB  = (bf16*)alloc((size_t)16384000 * 2);
    bf16* encWihB = (bf16*)alloc((size_t)2097152 * 2);
    bf16* encWhhB = (bf16*)alloc((size_t)4194304 * 2);
    bf16* decWihB = (bf16*)alloc((size_t)6291456 * 2);
    bf16* decWhhB = (bf16*)alloc((size_t)4194304 * 2);
    bf16* qkWB    = (bf16*)alloc((size_t)102400 * 2);
    bf16* qvWB    = (bf16*)alloc((size_t)1048576 * 2);
    bf16* outWB   = (bf16*)alloc((size_t)1048576 * 2);
    bf16* hfc1B   = (bf16*)alloc((size_t)2097152 * 2);
    bf16* hfc2B   = (bf16*)alloc((size_t)2097152 * 2);
    bf16* cfc1B   = (bf16*)alloc((size_t)2097152 * 2);
    bf16* cfc2B   = (bf16*)alloc((size_t)2097152 * 2);
    bf16*  Xsrc  = (bf16*)alloc((size_t)4096 * 512 * 2);
    bf16*  Zx    = (bf16*)alloc((size_t)4096 * 4096 * 2);
    bf16*  SH    = (bf16*)alloc((size_t)4096 * 1024 * 2);
    float* qkB   = (float*)alloc((size_t)4096 * 100 * 4);
    float* qvB   = (float*)alloc((size_t)4096 * 1024 * 4);
    bf16*  hbA   = (bf16*)alloc(32 * 1024 * 2);
    bf16*  hbB   = (bf16*)alloc(32 * 1024 * 2);
    bf16*  cbT   = (bf16*)alloc(32 * 1024 * 2);
    bf16*  t1    = (bf16*)alloc(32 * 2048 * 2);
    float* hd    = (float*)alloc(32 * 1024 * 4);
    float* cd    = (float*)alloc(32 * 1024 * 4);
    bf16*  hdA   = (bf16*)alloc(32 * 1024 * 2);
    bf16*  hdB   = (bf16*)alloc(32 * 1024 * 2);
    bf16*  xin   = (bf16*)alloc(32 * 1536 * 2);
    bf16*  featA = (bf16*)alloc(32 * 2048 * 2);
    bf16*  feats = (bf16*)alloc((size_t)608 * 512 * 2);
    int*   bar   = (int*)alloc(128 * 4);
    if ((size_t)(cur - (char*)d_ws) > ws_size) return;  // workspace too small

    hipMemsetAsync(hbA, 0, 32 * 1024 * 2, stream);
    hipMemsetAsync(bar, 0, 128 * 4, stream);

    ConvTable tab;
    tab.d[0]  = {embed,   embedB,  16384000};
    tab.d[1]  = {enc_Wih, encWihB, 2097152};
    tab.d[2]  = {enc_Whh, encWhhB, 4194304};
    tab.d[3]  = {dec_Wih, decWihB, 6291456};
    tab.d[4]  = {dec_Whh, decWhhB, 4194304};
    tab.d[5]  = {qk_W,    qkWB,    102400};
    tab.d[6]  = {qv_W,    qvWB,    1048576};
    tab.d[7]  = {out_W,   outWB,   1048576};
    tab.d[8]  = {hfc1_W,  hfc1B,   2097152};
    tab.d[9]  = {hfc2_W,  hfc2B,   2097152};
    tab.d[10] = {cfc1_W,  cfc1B,   2097152};
    tab.d[11] = {cfc2_W,  cfc2B,   2097152};
    k_conv<<<dim3(1024, 12), 256, 0, stream>>>(tab);

    k_gather<<<4096, 256, 0, stream>>>((const unsigned int*)embedB, src, (unsigned int*)Xsrc);

    // Zx = Xsrc @ enc_Wih^T  (M=4096, N=4096, K=512), bf16 out
    k_gemm_bt<<<32 * 32, 256, 0, stream>>>(Xsrc, encWihB, nullptr, nullptr, Zx,
                                           4096, 4096, 512, 4096, 32, 3);

    // Persistent encoder (cooperative launch for co-residency only).
    {
        const bf16* ZxA = Zx;  const bf16* WhhA = encWhhB;
        const float* bihA = enc_bih; const float* bhhA = enc_bhh;
        const int* lensA = lens;
        unsigned int* hb0A = (unsigned int*)hbA;
        unsigned int* hb1A = (unsigned int*)hbB;
        bf16* cbTA = cbT; bf16* SHA = SH; int* barA = bar;
        void* args[] = {(void*)&ZxA, (void*)&WhhA, (void*)&bihA, (void*)&bhhA,
                        (void*)&lensA, (void*)&hb0A, (void*)&hb1A, (void*)&cbTA,
                        (void*)&SHA, (void*)&barA};
        hipLaunchCooperativeKernel((void*)k_enc_all, dim3(64), dim3(256), args, 0, stream);
    }
    bf16* hbT = hbA;  // publish target at t=127 (odd) is hbw0 == hbA

    k_gemm_sm<<<256, 64, 0, stream>>>(hbT, hfc1B, hfc1_b, nullptr, 0, t1, 2048, 1024, 128, 1);
    k_gemm_sm<<<128, 64, 0, stream>>>(t1, hfc2B, hfc2_b, hd, 1024, hdA, 1024, 2048, 64, 0);
    k_gemm_sm<<<256, 64, 0, stream>>>(cbT, cfc1B, cfc1_b, nullptr, 0, t1, 2048, 1024, 128, 1);
    k_gemm_sm<<<128, 64, 0, stream>>>(t1, cfc2B, cfc2_b, cd, 1024, nullptr, 0, 2048, 64, 0);

    k_gemm_bt<<<32, 256, 0, stream>>>(SH, qkWB, qk_b, qkB, nullptr,
                                      4096, 100, 1024, 100, 1, 1);
    k_gemm_bt<<<256, 256, 0, stream>>>(SH, qvWB, qv_b, qvB, nullptr,
                                       4096, 1024, 1024, 1024, 8, 0);

    for (int t = 0; t < 19; ++t) {
        const bf16* hin = (t & 1) ? hdB : hdA;
        bf16* hout = (t & 1) ? hdA : hdB;
        k_attn<<<128, 256, 0, stream>>>(embedB, trg, ak_W, ak_b, qkB, qvB, lens, hd,
                                        xin, featA, t);
        k_dec_z<<<256, 64, 0, stream>>>(xin, decWihB, hin, decWhhB, dec_bih, dec_bhh,
                                        hd, cd, hout, featA);
        k_gemm_sm<<<64, 64, 0, stream>>>(featA, outWB, out_b, nullptr, 0,
                                         feats + (size_t)t * 32 * 512, 512, 2048, 32, 0);
    }

    k_gemm_bt<<<5 * 250, 256, 0, stream>>>(feats, embedB, wd_b, (float*)d_out, nullptr,
                                           608, 32000, 512, 0, 250, 2);
}

// Round 8
// 4304.372 us; speedup vs baseline: 1.1367x; 1.0501x over previous
//
#include <hip/hip_runtime.h>
#include <hip/hip_bf16.h>

// Problem constants: B=32, S=128, T=20 (19 dec steps), H=1024, D=512, K_attn=100, V=32000
// Inputs float32; output d_out float32 (B,19,V).
// bf16 MFMA with fp32 accumulate; recurrent state fp32 in registers.
// Encoder: EXACT round-4 kernel (passing at 2619us). Rounds 5-7 proved any
// batched pure-load scheduling of the staging atomics breaks correctness
// deterministically -- do not touch the staging loop.
// Decoder: a_key hoisted to a padded MFMA GEMM; qvB stored bf16; parallel softmax.

using bf16 = __hip_bfloat16;
typedef __attribute__((ext_vector_type(8))) __bf16 bf16x8;
typedef __attribute__((ext_vector_type(4))) float f32x4;

__device__ __forceinline__ bf16x8 ld8(const bf16* p) {
    return *reinterpret_cast<const bf16x8*>(p);
}
__device__ __forceinline__ float b2f(bf16 v) { return __bfloat162float(v); }
__device__ __forceinline__ bf16 f2b(float v) { return __float2bfloat16(v); }
__device__ __forceinline__ unsigned short b2u(bf16 v) {
    unsigned short u; __builtin_memcpy(&u, &v, 2); return u;
}
__device__ __forceinline__ float sigf(float x) { return 1.0f / (1.0f + expf(-x)); }

#define MFMA(a, b, c) __builtin_amdgcn_mfma_f32_16x16x32_bf16((a), (b), (c), 0, 0, 0)

// ---------------------------------------------------------------------------
// f32 -> bf16 conversion for weight tensors. blockIdx.y selects tensor.
struct ConvDesc { const float* src; bf16* dst; int n; };
struct ConvTable { ConvDesc d[13]; };

__global__ __launch_bounds__(256) void k_conv(ConvTable tab) {
    ConvDesc cd = tab.d[blockIdx.y];
    int stride = gridDim.x * blockDim.x * 4;
    for (int i = (blockIdx.x * blockDim.x + threadIdx.x) * 4; i < cd.n; i += stride) {
        float4 v = *reinterpret_cast<const float4*>(cd.src + i);
        bf16 tmp[4] = {f2b(v.x), f2b(v.y), f2b(v.z), f2b(v.w)};
        *reinterpret_cast<ushort4*>(cd.dst + i) = *reinterpret_cast<const ushort4*>(tmp);
    }
}

// ---------------------------------------------------------------------------
// Gather bf16 embedding rows (512 bf16 = 256 u32 per row), one block per row.
__global__ __launch_bounds__(256) void k_gather(const unsigned int* __restrict__ table,
                                                const int* __restrict__ idx,
                                                unsigned int* __restrict__ out) {
    int r = blockIdx.x;
    out[(size_t)r * 256 + threadIdx.x] = table[(size_t)idx[r] * 256 + threadIdx.x];
}

// ---------------------------------------------------------------------------
// Generic big tiled GEMM: C = A(MxK) @ Bw(NxK)^T  (both row-major, bf16)
// mode 0: outF fp32 = C + bias ; mode 1: tanh ; mode 2: logits remap ; mode 3: bf16+bias
// xcdmap=1: group M-tiles of one N-strip consecutively on one XCD (L2 reuse).
__global__ __launch_bounds__(256) void k_gemm_bt(const bf16* __restrict__ A,
                                                 const bf16* __restrict__ Bw,
                                                 const float* __restrict__ bias,
                                                 float* __restrict__ outF,
                                                 bf16* __restrict__ outB,
                                                 int M, int N, int K, int ldo,
                                                 int ntN, int mode, int xcdmap) {
    int bx = blockIdx.x;
    int mt, nt;
    if (xcdmap) {
        int ntM = (M + 127) >> 7;
        int x = bx & 7, w = bx >> 3;
        mt = w % ntM;
        nt = (w / ntM) * 8 + x;
        if (nt >= ntN) return;
    } else {
        mt = bx / ntN;
        nt = bx % ntN;
    }
    int tid = threadIdx.x, wv = tid >> 6, l = tid & 63;
    int m0 = mt * 128 + (wv >> 1) * 64;
    int n0 = nt * 128 + (wv & 1) * 64;
    int r = l & 15, ko = (l >> 4) * 8;

    const bf16* ap[4];
    const bf16* bp[4];
#pragma unroll
    for (int i = 0; i < 4; ++i) {
        int row = m0 + i * 16 + r;
        if (row > M - 1) row = M - 1;
        ap[i] = A + (size_t)row * K + ko;
    }
#pragma unroll
    for (int j = 0; j < 4; ++j) {
        int n = n0 + j * 16 + r;
        if (n > N - 1) n = N - 1;
        bp[j] = Bw + (size_t)n * K + ko;
    }

    f32x4 zv = {0.f, 0.f, 0.f, 0.f};
    f32x4 acc[4][4];
#pragma unroll
    for (int i = 0; i < 4; ++i)
#pragma unroll
        for (int j = 0; j < 4; ++j) acc[i][j] = zv;

    int nk = K >> 5;
    for (int kk = 0; kk < nk; ++kk) {
        bf16x8 af[4], bfv[4];
#pragma unroll
        for (int i = 0; i < 4; ++i) af[i] = ld8(ap[i] + kk * 32);
#pragma unroll
        for (int j = 0; j < 4; ++j) bfv[j] = ld8(bp[j] + kk * 32);
#pragma unroll
        for (int i = 0; i < 4; ++i)
#pragma unroll
            for (int j = 0; j < 4; ++j) acc[i][j] = MFMA(af[i], bfv[j], acc[i][j]);
    }

    int ccol = l & 15, cr = (l >> 4) * 4;
#pragma unroll
    for (int i = 0; i < 4; ++i) {
#pragma unroll
        for (int j = 0; j < 4; ++j) {
            int n = n0 + j * 16 + ccol;
            if (n >= N) continue;
            float bv = bias ? bias[n] : 0.f;
#pragma unroll
            for (int q = 0; q < 4; ++q) {
                int row = m0 + i * 16 + cr + q;
                if (row >= M) continue;
                float v = acc[i][j][q] + bv;
                if (mode == 1) v = tanhf(v);
                if (mode == 2) {
                    outF[((size_t)(row & 31) * 19 + (size_t)(row >> 5)) * 32000 + n] = v;
                } else if (mode == 3) {
                    outB[(size_t)row * ldo + n] = f2b(v);
                } else {
                    outF[(size_t)row * ldo + n] = v;
                }
            }
        }
    }
}

// ---------------------------------------------------------------------------
// Small-M GEMM: one 16x16 tile per block (64 threads = 1 wave).
// act: 0 none, 1 relu, 2 tanh.
__global__ __launch_bounds__(64) void k_gemm_sm(const bf16* __restrict__ A,
                                                const bf16* __restrict__ W,
                                                const float* __restrict__ bias,
                                                float* __restrict__ outF, int ldof,
                                                bf16* __restrict__ outB, int ldob,
                                                int K, int ntN, int act) {
    int bx = blockIdx.x;
    int mt = bx / ntN, nt = bx % ntN;
    int l = threadIdx.x;
    int r = l & 15, ko = (l >> 4) * 8;
    const bf16* ap = A + (size_t)(mt * 16 + r) * K + ko;
    const bf16* bp = W + (size_t)(nt * 16 + r) * K + ko;
    f32x4 acc = {0.f, 0.f, 0.f, 0.f};
    int nk = K >> 5;
#pragma unroll 4
    for (int kk = 0; kk < nk; ++kk) acc = MFMA(ld8(ap + kk * 32), ld8(bp + kk * 32), acc);
    int n = nt * 16 + (l & 15);
    int cr = (l >> 4) * 4;
    float bv = bias ? bias[n] : 0.f;
#pragma unroll
    for (int q = 0; q < 4; ++q) {
        int row = mt * 16 + cr + q;
        float v = acc[q] + bv;
        if (act == 1) v = fmaxf(v, 0.f);
        if (act == 2) v = tanhf(v);
        if (outF) outF[(size_t)row * ldof + n] = v;
        if (outB) outB[(size_t)row * ldob + n] = f2b(v);
    }
}

// ---------------------------------------------------------------------------
// Persistent encoder, 128 LSTM steps. EXACT round-4 kernel (passing).
// Grid 64 blocks x 256 thr (4 waves = 4 gates). Whh j-slice in registers.
// DO NOT reschedule the staging loop (rounds 5-7: deterministic corruption).
__global__ __launch_bounds__(256, 1) void k_enc_all(const bf16* __restrict__ Zx,
                                                    const bf16* __restrict__ Whh,
                                                    const float* __restrict__ bih,
                                                    const float* __restrict__ bhh,
                                                    const int* __restrict__ lens,
                                                    unsigned int* __restrict__ hbw0,
                                                    unsigned int* __restrict__ hbw1,
                                                    bf16* __restrict__ cbT,
                                                    bf16* __restrict__ SH,
                                                    int* __restrict__ bar) {
    __shared__ bf16 hlds[32][1024];          // 64KB staged h, XOR-swizzled 16B units
    __shared__ float zl[4][32][16];          // 8KB gate outputs
    __shared__ unsigned short hpub[32][16];  // 1KB publish staging
    unsigned int* hldsw = (unsigned int*)hlds;
    const bf16x8* hldsv = (const bf16x8*)hlds;

    int j0 = blockIdx.x * 16;
    int tid = threadIdx.x;
    int g = tid >> 6, l = tid & 63;
    int r = l & 15, ko = (l >> 4) * 8;

    // Whh slice -> registers (16 rows x 1024 K per wave), loaded once.
    bf16x8 wreg[32];
    {
        const bf16* wp = Whh + (size_t)(g * 1024 + j0 + r) * 1024 + ko;
#pragma unroll
        for (int kk = 0; kk < 32; ++kk) wreg[kk] = ld8(wp + kk * 32);
    }

    int b0 = tid >> 4, ji = tid & 15;
    int b1 = b0 + 16;
    int j = j0 + ji;
    float bs[4];
#pragma unroll
    for (int gg = 0; gg < 4; ++gg) bs[gg] = bih[gg * 1024 + j] + bhh[gg * 1024 + j];
    int len0 = lens[b0], len1 = lens[b1];
    float h0 = 0.f, c0 = 0.f, h1 = 0.f, c1 = 0.f;
    const bf16* zx0 = Zx + (size_t)(b0 * 128) * 4096 + j;
    const bf16* zx1 = Zx + (size_t)(b1 * 128) * 4096 + j;
    int ccol = l & 15, cr = (l >> 4) * 4;
    int rk = r & 7;  // XOR swizzle key (same for rows r and r+16)

    for (int t = 0; t < 128; ++t) {
        // Prefetch Zx[t] (independent of barrier) — hides LLC latency under spin.
        float za0[4], za1[4];
#pragma unroll
        for (int gg = 0; gg < 4; ++gg) {
            za0[gg] = b2f(zx0[(size_t)t * 4096 + gg * 1024]);
            za1[gg] = b2f(zx1[(size_t)t * 4096 + gg * 1024]);
        }

        // Wait for all producers of h_t (t=0: initial zeros from memset).
        if (t > 0) {
            if (tid == 0) {
                while (__hip_atomic_load(bar + (t - 1), __ATOMIC_RELAXED,
                                         __HIP_MEMORY_SCOPE_AGENT) < 64)
                    __builtin_amdgcn_s_sleep(1);
                (void)__hip_atomic_load(bar + (t - 1), __ATOMIC_ACQUIRE,
                                        __HIP_MEMORY_SCOPE_AGENT);
            }
            __syncthreads();
        }

        // Stage h_t (64KB) LLC -> LDS, swizzled: unit u -> u ^ (row & 7).
        const unsigned int* hw = (t & 1) ? hbw1 : hbw0;
#pragma unroll 4
        for (int i = 0; i < 64; ++i) {
            int d = i * 256 + tid;
            int b = d >> 9, w = d & 511;
            unsigned int v = __hip_atomic_load(hw + d, __ATOMIC_RELAXED,
                                               __HIP_MEMORY_SCOPE_AGENT);
            hldsw[b * 512 + ((((w >> 2) ^ (b & 7)) << 2) | (w & 3))] = v;
        }
        __syncthreads();

        // z[g] slice = h @ Whh[g-slice]^T from LDS.
        f32x4 acc0 = {0.f, 0.f, 0.f, 0.f}, acc1 = {0.f, 0.f, 0.f, 0.f};
#pragma unroll
        for (int kk = 0; kk < 32; ++kk) {
            int u = kk * 4 + (l >> 4);
            acc0 = MFMA(hldsv[r * 128 + (u ^ rk)], wreg[kk], acc0);
            acc1 = MFMA(hldsv[(16 + r) * 128 + (u ^ rk)], wreg[kk], acc1);
        }
#pragma unroll
        for (int q = 0; q < 4; ++q) {
            zl[g][cr + q][ccol] = acc0[q];
            zl[g][16 + cr + q][ccol] = acc1[q];
        }
        __syncthreads();

        // Fused pointwise: this thread owns (b0,j) and (b1,j).
        {
            float zi = zl[0][b0][ji] + za0[0] + bs[0];
            float zf = zl[1][b0][ji] + za0[1] + bs[1];
            float zg = zl[2][b0][ji] + za0[2] + bs[2];
            float zo = zl[3][b0][ji] + za0[3] + bs[3];
            float cn = sigf(zf) * c0 + sigf(zi) * tanhf(zg);
            float hn = sigf(zo) * tanhf(cn);
            bool msk = t < len0;
            if (msk) { h0 = hn; c0 = cn; }
            hpub[b0][ji] = b2u(f2b(h0));
            SH[((size_t)b0 * 128 + t) * 1024 + j] = msk ? f2b(hn) : f2b(0.f);
        }
        {
            float zi = zl[0][b1][ji] + za1[0] + bs[0];
            float zf = zl[1][b1][ji] + za1[1] + bs[1];
            float zg = zl[2][b1][ji] + za1[2] + bs[2];
            float zo = zl[3][b1][ji] + za1[3] + bs[3];
            float cn = sigf(zf) * c1 + sigf(zi) * tanhf(zg);
            float hn = sigf(zo) * tanhf(cn);
            bool msk = t < len1;
            if (msk) { h1 = hn; c1 = cn; }
            hpub[b1][ji] = b2u(f2b(h1));
            SH[((size_t)b1 * 128 + t) * 1024 + j] = msk ? f2b(hn) : f2b(0.f);
        }
        if (t == 127) {
            cbT[b0 * 1024 + j] = f2b(c0);
            cbT[b1 * 1024 + j] = f2b(c1);
        }
        __syncthreads();

        // Publish this block's h_{t+1} slice (32 b x 16 j = 256 u32) to LLC.
        unsigned int* hwn = (t & 1) ? hbw0 : hbw1;
        {
            int pb = tid >> 3, pw = tid & 7;
            unsigned int val = (unsigned int)hpub[pb][2 * pw] |
                               ((unsigned int)hpub[pb][2 * pw + 1] << 16);
            __hip_atomic_store(hwn + (size_t)pb * 512 + (j0 >> 1) + pw, val,
                               __ATOMIC_RELAXED, __HIP_MEMORY_SCOPE_AGENT);
        }
        __syncthreads();  // per-wave vmcnt(0) drained before barrier => stores acked
        if (tid == 0)
            __hip_atomic_fetch_add(bar + t, 1, __ATOMIC_RELEASE,
                                   __HIP_MEMORY_SCOPE_AGENT);
    }
}

// ---------------------------------------------------------------------------
// Decoder attention step. Grid 128 = 32 batches x 4 j-chunks (256 cols each).
// a_key precomputed (akey, 32x112 fp32, first 100 valid); qvB in bf16.
__global__ __launch_bounds__(256) void k_attn(const bf16* __restrict__ embedB,
                                              const int* __restrict__ trg,
                                              const float* __restrict__ akey,
                                              const float* __restrict__ qkB,
                                              const bf16* __restrict__ qvBb,
                                              const int* __restrict__ lens,
                                              bf16* __restrict__ xin,
                                              bf16* __restrict__ featA, int t) {
    int b = blockIdx.x >> 2, chunk = blockIdx.x & 3;
    int tid = threadIdx.x;
    if (chunk == 0) {
        const unsigned int* er = (const unsigned int*)(embedB + (size_t)trg[b * 20 + t] * 512);
        ((unsigned int*)(xin + (size_t)b * 1536))[tid] = er[tid];
    }

    __shared__ float ak[100];
    __shared__ float ew[128];
    __shared__ float mxs, inv_s;

    if (tid < 100) ak[tid] = akey[b * 112 + tid];
    __syncthreads();

    if (tid < 128) {
        const float* qr = qkB + ((size_t)b * 128 + tid) * 100;
        float e = 0.f;
#pragma unroll 4
        for (int k = 0; k < 100; ++k) e += qr[k] * ak[k];
        ew[tid] = (tid < lens[b]) ? e : -INFINITY;
    }
    __syncthreads();
    if (tid < 64) {
        float m = fmaxf(ew[tid], ew[tid + 64]);
#pragma unroll
        for (int off = 32; off; off >>= 1) m = fmaxf(m, __shfl_down(m, off));
        if (tid == 0) mxs = m;
    }
    __syncthreads();
    if (tid < 128) ew[tid] = expf(ew[tid] - mxs);  // masked -> 0
    __syncthreads();
    if (tid < 64) {
        float s = ew[tid] + ew[tid + 64];
#pragma unroll
        for (int off = 32; off; off >>= 1) s += __shfl_down(s, off);
        if (tid == 0) inv_s = 1.0f / s;
    }
    __syncthreads();

    {
        int jj = (chunk << 8) + tid;
        const bf16* qvb = qvBb + ((size_t)b * 128) * 1024 + jj;
        float a0 = 0.f;
#pragma unroll 4
        for (int s2 = 0; s2 < 128; ++s2) a0 += ew[s2] * b2f(qvb[(size_t)s2 * 1024]);
        a0 *= inv_s;
        bf16 cb = f2b(a0);
        xin[(size_t)b * 1536 + 512 + jj] = cb;
        featA[(size_t)b * 2048 + 1024 + jj] = cb;
    }
}

// ---------------------------------------------------------------------------
// Decoder LSTM step. Grid 256 blocks x 64 thr; gates x 4 j packed in N-tile.
// h state carried as bf16 (hb_in/hb_out); c state fp32 (cd).
__global__ __launch_bounds__(64) void k_dec_z(const bf16* __restrict__ xin,
                                              const bf16* __restrict__ Wih,
                                              const bf16* __restrict__ hb_in,
                                              const bf16* __restrict__ Whh,
                                              const float* __restrict__ bih,
                                              const float* __restrict__ bhh,
                                              float* __restrict__ cd,
                                              bf16* __restrict__ hb_out,
                                              bf16* __restrict__ featA) {
    __shared__ float zl[32][16];
    int j0 = blockIdx.x * 4;
    int l = threadIdx.x;
    int r = l & 15, ko = (l >> 4) * 8;
    int wrow = (r >> 2) * 1024 + j0 + (r & 3);

    f32x4 acc0 = {0.f, 0.f, 0.f, 0.f}, acc1 = {0.f, 0.f, 0.f, 0.f};
    {
        const bf16* a0 = xin + (size_t)r * 1536 + ko;
        const bf16* a1 = xin + (size_t)(16 + r) * 1536 + ko;
        const bf16* bp = Wih + (size_t)wrow * 1536 + ko;
#pragma unroll 4
        for (int kk = 0; kk < 48; ++kk) {
            bf16x8 bv = ld8(bp + kk * 32);
            acc0 = MFMA(ld8(a0 + kk * 32), bv, acc0);
            acc1 = MFMA(ld8(a1 + kk * 32), bv, acc1);
        }
    }
    {
        const bf16* a0 = hb_in + (size_t)r * 1024 + ko;
        const bf16* a1 = hb_in + (size_t)(16 + r) * 1024 + ko;
        const bf16* bp = Whh + (size_t)wrow * 1024 + ko;
#pragma unroll 4
        for (int kk = 0; kk < 32; ++kk) {
            bf16x8 bv = ld8(bp + kk * 32);
            acc0 = MFMA(ld8(a0 + kk * 32), bv, acc0);
            acc1 = MFMA(ld8(a1 + kk * 32), bv, acc1);
        }
    }
    int ccol = l & 15, cr = (l >> 4) * 4;
#pragma unroll
    for (int q = 0; q < 4; ++q) {
        zl[cr + q][ccol] = acc0[q];
        zl[16 + cr + q][ccol] = acc1[q];
    }
    __syncthreads();

#pragma unroll
    for (int e = l; e < 128; e += 64) {
        int b = e >> 2, jj = e & 3;
        int j = j0 + jj;
        float zi = zl[b][jj]      + bih[j]        + bhh[j];
        float zf = zl[b][4 + jj]  + bih[1024 + j] + bhh[1024 + j];
        float zg = zl[b][8 + jj]  + bih[2048 + j] + bhh[2048 + j];
        float zo = zl[b][12 + jj] + bih[3072 + j] + bhh[3072 + j];
        int hi = b * 1024 + j;
        float co = cd[hi];
        float cn = sigf(zf) * co + sigf(zi) * tanhf(zg);
        float hn = sigf(zo) * tanhf(cn);
        cd[hi] = cn;
        hb_out[hi] = f2b(hn);
        featA[(size_t)b * 2048 + j] = f2b(hn);
    }
}

// ---------------------------------------------------------------------------
extern "C" void kernel_launch(void* const* d_in, const int* in_sizes, int n_in,
                              void* d_out, int out_size, void* d_ws, size_t ws_size,
                              hipStream_t stream) {
    const float* embed   = (const float*)d_in[0];
    const float* enc_Wih = (const float*)d_in[1];
    const float* enc_Whh = (const float*)d_in[2];
    const float* enc_bih = (const float*)d_in[3];
    const float* enc_bhh = (const float*)d_in[4];
    const float* dec_Wih = (const float*)d_in[5];
    const float* dec_Whh = (const float*)d_in[6];
    const float* dec_bih = (const float*)d_in[7];
    const float* dec_bhh = (const float*)d_in[8];
    const float* qk_W    = (const float*)d_in[9];
    const float* qk_b    = (const float*)d_in[10];
    const float* qv_W    = (const float*)d_in[11];
    const float* qv_b    = (const float*)d_in[12];
    const float* ak_W    = (const float*)d_in[13];
    const float* ak_b    = (const float*)d_in[14];
    const float* out_W   = (const float*)d_in[15];
    const float* out_b   = (const float*)d_in[16];
    const float* wd_b    = (const float*)d_in[17];
    const float* hfc1_W  = (const float*)d_in[18];
    const float* hfc1_b  = (const float*)d_in[19];
    const float* hfc2_W  = (const float*)d_in[20];
    const float* hfc2_b  = (const float*)d_in[21];
    const float* cfc1_W  = (const float*)d_in[22];
    const float* cfc1_b  = (const float*)d_in[23];
    const float* cfc2_W  = (const float*)d_in[24];
    const float* cfc2_b  = (const float*)d_in[25];
    const int* src  = (const int*)d_in[26];
    const int* lens = (const int*)d_in[27];
    const int* trg  = (const int*)d_in[28];

    char* cur = (char*)d_ws;
    auto alloc = [&](size_t bytes) -> char* {
        char* p = cur;
        cur += (bytes + 255) & ~(size_t)255;
        return p;
    };
    bf16* embedB  = (bf16*)alloc((size_t)16384000 * 2);
    bf16* encWihB = (bf16*)alloc((size_t)2097152 * 2);
    bf16* encWhhB = (bf16*)alloc((size_t)4194304 * 2);
    bf16* decWihB = (bf16*)alloc((size_t)6291456 * 2);
    bf16* decWhhB = (bf16*)alloc((size_t)4194304 * 2);
    bf16* qkWB    = (bf16*)alloc((size_t)102400 * 2);
    bf16* qvWB    = (bf16*)alloc((size_t)1048576 * 2);
    bf16* outWB   = (bf16*)alloc((size_t)1048576 * 2);
    bf16* hfc1B   = (bf16*)alloc((size_t)2097152 * 2);
    bf16* hfc2B   = (bf16*)alloc((size_t)2097152 * 2);
    bf16* cfc1B   = (bf16*)alloc((size_t)2097152 * 2);
    bf16* cfc2B   = (bf16*)alloc((size_t)2097152 * 2);
    bf16* akWP    = (bf16*)alloc((size_t)112 * 1024 * 2);   // padded ak_W (112 rows)
    bf16*  Xsrc  = (bf16*)alloc((size_t)4096 * 512 * 2);
    bf16*  Zx    = (bf16*)alloc((size_t)4096 * 4096 * 2);
    bf16*  SH    = (bf16*)alloc((size_t)4096 * 1024 * 2);
    float* qkB   = (float*)alloc((size_t)4096 * 100 * 4);
    bf16*  qvBb  = (bf16*)alloc((size_t)4096 * 1024 * 2);   // q_value in bf16
    float* akey  = (float*)alloc((size_t)32 * 112 * 4);
    float* akbP  = (float*)alloc(112 * 4);
    bf16*  hbA   = (bf16*)alloc(32 * 1024 * 2);
    bf16*  hbB   = (bf16*)alloc(32 * 1024 * 2);
    bf16*  cbT   = (bf16*)alloc(32 * 1024 * 2);
    bf16*  t1    = (bf16*)alloc(32 * 2048 * 2);
    float* cd    = (float*)alloc(32 * 1024 * 4);
    bf16*  hdA   = (bf16*)alloc(32 * 1024 * 2);
    bf16*  hdB   = (bf16*)alloc(32 * 1024 * 2);
    bf16*  xin   = (bf16*)alloc(32 * 1536 * 2);
    bf16*  featA = (bf16*)alloc(32 * 2048 * 2);
    bf16*  feats = (bf16*)alloc((size_t)608 * 512 * 2);
    int*   bar   = (int*)alloc(128 * 4);
    if ((size_t)(cur - (char*)d_ws) > ws_size) return;  // workspace too small

    hipMemsetAsync(hbA, 0, 32 * 1024 * 2, stream);
    hipMemsetAsync(bar, 0, 128 * 4, stream);
    hipMemsetAsync(akbP, 0, 112 * 4, stream);
    hipMemcpyAsync(akbP, ak_b, 100 * 4, hipMemcpyDeviceToDevice, stream);

    ConvTable tab;
    tab.d[0]  = {embed,   embedB,  16384000};
    tab.d[1]  = {enc_Wih, encWihB, 2097152};
    tab.d[2]  = {enc_Whh, encWhhB, 4194304};
    tab.d[3]  = {dec_Wih, decWihB, 6291456};
    tab.d[4]  = {dec_Whh, decWhhB, 4194304};
    tab.d[5]  = {qk_W,    qkWB,    102400};
    tab.d[6]  = {qv_W,    qvWB,    1048576};
    tab.d[7]  = {out_W,   outWB,   1048576};
    tab.d[8]  = {hfc1_W,  hfc1B,   2097152};
    tab.d[9]  = {hfc2_W,  hfc2B,   2097152};
    tab.d[10] = {cfc1_W,  cfc1B,   2097152};
    tab.d[11] = {cfc2_W,  cfc2B,   2097152};
    tab.d[12] = {ak_W,    akWP,    102400};   // pad rows 100-111 unread
    k_conv<<<dim3(1024, 13), 256, 0, stream>>>(tab);

    k_gather<<<4096, 256, 0, stream>>>((const unsigned int*)embedB, src, (unsigned int*)Xsrc);

    // Zx = Xsrc @ enc_Wih^T  (M=4096, N=4096, K=512), bf16 out
    k_gemm_bt<<<32 * 32, 256, 0, stream>>>(Xsrc, encWihB, nullptr, nullptr, Zx,
                                           4096, 4096, 512, 4096, 32, 3, 0);

    // Persistent encoder (cooperative launch for co-residency only).
    {
        const bf16* ZxA = Zx;  const bf16* WhhA = encWhhB;
        const float* bihA = enc_bih; const float* bhhA = enc_bhh;
        const int* lensA = lens;
        unsigned int* hb0A = (unsigned int*)hbA;
        unsigned int* hb1A = (unsigned int*)hbB;
        bf16* cbTA = cbT; bf16* SHA = SH; int* barA = bar;
        void* args[] = {(void*)&ZxA, (void*)&WhhA, (void*)&bihA, (void*)&bhhA,
                        (void*)&lensA, (void*)&hb0A, (void*)&hb1A, (void*)&cbTA,
                        (void*)&SHA, (void*)&barA};
        hipLaunchCooperativeKernel((void*)k_enc_all, dim3(64), dim3(256), args, 0, stream);
    }
    bf16* hbT = hbA;  // publish target at t=127 (odd) is hbw0 == hbA

    k_gemm_sm<<<256, 64, 0, stream>>>(hbT, hfc1B, hfc1_b, nullptr, 0, t1, 2048, 1024, 128, 1);
    k_gemm_sm<<<128, 64, 0, stream>>>(t1, hfc2B, hfc2_b, nullptr, 0, hdA, 1024, 2048, 64, 0);
    k_gemm_sm<<<256, 64, 0, stream>>>(cbT, cfc1B, cfc1_b, nullptr, 0, t1, 2048, 1024, 128, 1);
    k_gemm_sm<<<128, 64, 0, stream>>>(t1, cfc2B, cfc2_b, cd, 1024, nullptr, 0, 2048, 64, 0);

    k_gemm_bt<<<32, 256, 0, stream>>>(SH, qkWB, qk_b, qkB, nullptr,
                                      4096, 100, 1024, 100, 1, 1, 0);
    k_gemm_bt<<<256, 256, 0, stream>>>(SH, qvWB, qv_b, nullptr, qvBb,
                                       4096, 1024, 1024, 1024, 8, 3, 0);

    for (int t = 0; t < 19; ++t) {
        const bf16* hin = (t & 1) ? hdB : hdA;
        bf16* hout = (t & 1) ? hdA : hdB;
        // a_key = tanh(h @ ak_W^T + ak_b): padded 32x112 MFMA GEMM
        k_gemm_sm<<<14, 64, 0, stream>>>(hin, akWP, akbP, akey, 112, nullptr, 0,
                                         1024, 7, 2);
        k_attn<<<128, 256, 0, stream>>>(embedB, trg, akey, qkB, qvBb, lens,
                                        xin, featA, t);
        k_dec_z<<<256, 64, 0, stream>>>(xin, decWihB, hin, decWhhB, dec_bih, dec_bhh,
                                        cd, hout, featA);
        k_gemm_sm<<<64, 64, 0, stream>>>(featA, outWB, out_b, nullptr, 0,
                                         feats + (size_t)t * 32 * 512, 512, 2048, 32, 0);
    }

    // Logits: feats(608x512) @ embed^T(32000x512) + wd_b, XCD-grouped mapping.
    k_gemm_bt<<<1280, 256, 0, stream>>>(feats, embedB, wd_b, (float*)d_out, nullptr,
                                        608, 32000, 512, 0, 250, 2, 1);
}